// Round 1
// baseline (1269.384 us; speedup 1.0000x reference)
//
#include <hip/hip_runtime.h>
#include <cstddef>

// Shapes: B=64, C=128, Ch=64, H=W=56, N=3136, G=2, K=3, heads=2, hd=32, Nk=196, inner=16
#define NPIX 3136

__device__ __forceinline__ float gelu_f(float x){
  return 0.5f*x*(1.0f+erff(x*0.70710678118654752440f));
}

// ---------------- K1: adaptive_avg_pool(3x3, overlapping regions) + full mean ----------------
// grid: B*64 (b,c of x1), block: 64 (one wave)
__global__ void k_pool(const float* __restrict__ x, float* __restrict__ pooled, float* __restrict__ xmean){
  int b = blockIdx.x >> 6, c = blockIdx.x & 63;
  const float* xp = x + ((size_t)(b*128 + c))*NPIX;
  float r[9] = {0,0,0,0,0,0,0,0,0};
  float tot = 0.f;
  for (int p = threadIdx.x; p < NPIX; p += 64){
    float v = xp[p];
    int h = p/56, w = p%56;
    tot += v;
    // regions: [0,19),[18,38),[37,56)
    bool h0 = (h<=18), h1 = (h>=18 && h<=37), h2 = (h>=37);
    bool w0 = (w<=18), w1 = (w>=18 && w<=37), w2 = (w>=37);
    if(h0){ if(w0) r[0]+=v; if(w1) r[1]+=v; if(w2) r[2]+=v; }
    if(h1){ if(w0) r[3]+=v; if(w1) r[4]+=v; if(w2) r[5]+=v; }
    if(h2){ if(w0) r[6]+=v; if(w1) r[7]+=v; if(w2) r[8]+=v; }
  }
  #pragma unroll
  for (int o=32;o>0;o>>=1){
    #pragma unroll
    for (int k=0;k<9;k++) r[k]+=__shfl_xor(r[k],o);
    tot += __shfl_xor(tot,o);
  }
  if (threadIdx.x==0){
    const float cs[3]={19.f,20.f,19.f};
    #pragma unroll
    for(int i=0;i<3;i++)
      #pragma unroll
      for(int j=0;j<3;j++)
        pooled[(size_t)blockIdx.x*9 + i*3+j] = r[i*3+j]/(cs[i]*cs[j]);
    xmean[blockIdx.x] = tot*(1.f/3136.f);
  }
}

// ---------------- K2: dc_proj on pooled + on mean; softmax over G; build weight + dyn_bias ----
// grid: B, block: 256
__global__ void k_dcproj(const float* __restrict__ pooled, const float* __restrict__ xmean,
    const float* __restrict__ dcp1_w, const float* __restrict__ dcp1_g, const float* __restrict__ dcp1_b,
    const float* __restrict__ dcp2_w, const float* __restrict__ dcp2_b,
    const float* __restrict__ dc_w, const float* __restrict__ dc_b,
    float* __restrict__ weightO, float* __restrict__ dyn_bias){
  int b = blockIdx.x; int tid = threadIdx.x;
  __shared__ float sp[576], sm[64], t1[144], t1b[16], s2[1152], s2b[128];
  for (int i=tid;i<576;i+=256) sp[i]=pooled[(size_t)b*576+i];
  if (tid<64) sm[tid]=xmean[b*64+tid];
  __syncthreads();
  for (int idx=tid; idx<160; idx+=256){
    if (idx<144){
      int o=idx/9, pos=idx%9; float s=0.f;
      for(int c2=0;c2<64;c2++) s += sp[c2*9+pos]*dcp1_w[o*64+c2];
      t1[idx]=gelu_f(s*dcp1_g[o]+dcp1_b[o]);
    } else {
      int o=idx-144; float s=0.f;
      for(int c2=0;c2<64;c2++) s+=sm[c2]*dcp1_w[o*64+c2];
      t1b[o]=gelu_f(s*dcp1_g[o]+dcp1_b[o]);
    }
  }
  __syncthreads();
  for (int idx=tid; idx<1280; idx+=256){
    if (idx<1152){
      int o=idx/9,pos=idx%9; float s=dcp2_b[o];
      #pragma unroll
      for(int i=0;i<16;i++) s+=t1[i*9+pos]*dcp2_w[o*16+i];
      s2[idx]=s;
    } else {
      int o=idx-1152; float s=dcp2_b[o];
      #pragma unroll
      for(int i=0;i<16;i++) s+=t1b[i]*dcp2_w[o*16+i];
      s2b[o]=s;
    }
  }
  __syncthreads();
  for (int idx=tid; idx<640; idx+=256){
    if (idx<576){
      int ch=idx/9, pos=idx%9;
      float a=s2[ch*9+pos], bb=s2[(64+ch)*9+pos];
      float m=fmaxf(a,bb); float e0=expf(a-m), e1=expf(bb-m); float w0=e0/(e0+e1);
      weightO[(size_t)b*576+idx] = w0*dc_w[ch*9+pos] + (1.f-w0)*dc_w[576+ch*9+pos];
    } else {
      int ch=idx-576;
      float a=s2b[ch], bb=s2b[64+ch];
      float m=fmaxf(a,bb); float e0=expf(a-m), e1=expf(bb-m); float w0=e0/(e0+e1);
      dyn_bias[b*64+ch] = w0*dc_b[ch] + (1.f-w0)*dc_b[64+ch];
    }
  }
}

// ---------------- K3: dynamic depthwise 3x3 conv on x1 -> y[:, :64] ----------------
// grid: B*64, block: 256
__global__ void k_y1(const float* __restrict__ x, const float* __restrict__ weightO,
                     const float* __restrict__ dyn_bias, float* __restrict__ y){
  int b = blockIdx.x>>6, c = blockIdx.x&63;
  __shared__ float pl[NPIX];
  const float* xp = x + ((size_t)(b*128+c))*NPIX;
  for (int p=threadIdx.x;p<NPIX;p+=256) pl[p]=xp[p];
  float w9[9];
  #pragma unroll
  for (int k=0;k<9;k++) w9[k]=weightO[(size_t)blockIdx.x*9+k];
  float bias = dyn_bias[blockIdx.x];
  __syncthreads();
  float* yp = y + ((size_t)(b*128+c))*NPIX;
  for (int p=threadIdx.x;p<NPIX;p+=256){
    int h=p/56, w=p%56;
    float acc=bias;
    #pragma unroll
    for (int i=0;i<3;i++){ int hh=h+i-1; if((unsigned)hh<56u){
      #pragma unroll
      for(int j=0;j<3;j++){ int ww=w+j-1; if((unsigned)ww<56u) acc += pl[hh*56+ww]*w9[i*3+j]; } } }
    yp[p]=acc;
  }
}

// ---------------- K4: q projection (x2 64ch -> 64ch), store q[(b,h,n,d)] ----------------
// grid: B*49, block: 256
__global__ void k_qproj(const float* __restrict__ x, const float* __restrict__ q_w,
                        const float* __restrict__ q_b, float* __restrict__ q){
  int b = blockIdx.x/49, t = blockIdx.x%49; int n0 = t*64; int tid = threadIdx.x;
  __shared__ float qwT[64*64]; // [c][o]
  __shared__ float xt[64*64];  // [c][p]
  for (int idx=tid; idx<4096; idx+=256){ int o=idx>>6, c2=idx&63; qwT[c2*64+o]=q_w[idx]; }
  for (int idx=tid; idx<4096; idx+=256){ int c2=idx>>6, p=idx&63;
    xt[idx]= x[((size_t)(b*128+64+c2))*NPIX + n0+p]; }
  __syncthreads();
  int od = tid&63;
  float qb = q_b[od];
  for (int p = tid>>6; p<64; p+=4){
    float acc=qb;
    #pragma unroll 8
    for (int c2=0;c2<64;c2++) acc += xt[c2*64+p]*qwT[c2*64+od];
    q[(((size_t)(b*2+(od>>5)))*NPIX + n0+p)*32 + (od&31)] = acc;
  }
}

// ---------------- K5a: 7x7 stride4 pad3 depthwise + BN/GELU + sr2 BN -> kv2 (B,64,14,14) -----
// grid: B*64, block: 256
__global__ void k_sr(const float* __restrict__ x, const float* __restrict__ sr1_w,
                     const float* __restrict__ sr1_g, const float* __restrict__ sr1_b,
                     const float* __restrict__ sr2_w, const float* __restrict__ sr2_g,
                     const float* __restrict__ sr2_b, float* __restrict__ kv2){
  int b=blockIdx.x>>6, c=blockIdx.x&63;
  __shared__ float pl[NPIX];
  const float* xp = x + ((size_t)(b*128+64+c))*NPIX;
  for (int p=threadIdx.x;p<NPIX;p+=256) pl[p]=xp[p];
  __syncthreads();
  int t=threadIdx.x;
  if (t<196){
    int oy=t/14, ox=t%14;
    float acc=0.f;
    #pragma unroll
    for(int i=0;i<7;i++){ int yy=oy*4-3+i; if((unsigned)yy<56u){
      #pragma unroll
      for(int j=0;j<7;j++){ int xx=ox*4-3+j; if((unsigned)xx<56u) acc += pl[yy*56+xx]*sr1_w[c*49+i*7+j]; } } }
    float g = gelu_f(acc*sr1_g[c]+sr1_b[c]);
    kv2[(size_t)blockIdx.x*196+t] = (g*sr2_w[c])*sr2_g[c]+sr2_b[c];
  }
}

// ---------------- K5b: 3x3 depthwise residual on kv2 -> kv3 ----------------
// grid: B*64, block: 256
__global__ void k_lc(const float* __restrict__ kv2, const float* __restrict__ lc_w,
                     const float* __restrict__ lc_b, float* __restrict__ kv3){
  int c=blockIdx.x&63;
  __shared__ float pl[196];
  for (int p=threadIdx.x;p<196;p+=256) pl[p]=kv2[(size_t)blockIdx.x*196+p];
  __syncthreads();
  int t=threadIdx.x;
  if (t<196){
    int oy=t/14, ox=t%14; float acc=lc_b[c]+pl[t];
    #pragma unroll
    for(int i=0;i<3;i++){int yy=oy+i-1; if((unsigned)yy<14u){
      #pragma unroll
      for(int j=0;j<3;j++){int xx=ox+j-1; if((unsigned)xx<14u) acc+=pl[yy*14+xx]*lc_w[c*9+i*3+j];}}}
    kv3[(size_t)blockIdx.x*196+t]=acc;
  }
}

// ---------------- K5c: kv pointwise 64->128, split K/V in [m][d] layout ----------------
// grid: B, block: 256
__global__ void k_kv(const float* __restrict__ kv3, const float* __restrict__ kv_w,
                     const float* __restrict__ kv_b, float* __restrict__ kws, float* __restrict__ vws){
  int b=blockIdx.x; int tid=threadIdx.x;
  __shared__ float s[64*196];
  for (int i=tid;i<12544;i+=256) s[i]=kv3[(size_t)b*12544+i];
  __syncthreads();
  for (int idx=tid; idx<128*196; idx+=256){
    int o=idx/196, m=idx%196;
    float acc=kv_b[o];
    #pragma unroll 8
    for(int c2=0;c2<64;c2++) acc += s[c2*196+m]*kv_w[o*64+c2];
    int h=(o>>5)&1, d=o&31;
    if (o<64) kws[(((size_t)(b*2+h))*196+m)*32+d] = acc;
    else      vws[(((size_t)(b*2+h))*196+m)*32+d] = acc;
  }
}

// ---------------- K6: attention (per (b,h), 64-row tile): QK^T*sc+rpe -> softmax -> @V -------
// grid: 49*128 (tile-major for rpe L2 reuse), block: 256
__global__ void k_attn(const float* __restrict__ q, const float* __restrict__ kws,
                       const float* __restrict__ vws, const float* __restrict__ rpe,
                       float* __restrict__ y){
  __shared__ float Ks[196*33];
  __shared__ float Vs[196*33];
  __shared__ float qs[64*32];
  __shared__ float Ss[64*201];
  int bh = blockIdx.x & 127;      // tile-major: 128 consecutive blocks share rpe rows
  int tile = blockIdx.x >> 7;
  int b=bh>>1, h=bh&1; int n0=tile*64;
  int tid=threadIdx.x;
  const float* kp = kws + (size_t)bh*6272;
  const float* vp = vws + (size_t)bh*6272;
  for (int i=tid;i<6272;i+=256){ int m=i>>5, d=i&31; Ks[m*33+d]=kp[i]; Vs[m*33+d]=vp[i]; }
  const float* qp = q + ((size_t)bh*NPIX + n0)*32;
  for (int i=tid;i<2048;i+=256) qs[i]=qp[i];
  __syncthreads();

  int wv = tid>>6, l = tid&63;
  const float sc = 0.17677669529663687f; // 1/sqrt(32)
  for (int g=0; g<4; ++g){
    int r0 = wv*16 + g*4;
    float acc[4][4];
    #pragma unroll
    for(int i=0;i<4;i++){ acc[i][0]=0;acc[i][1]=0;acc[i][2]=0;acc[i][3]=0; }
    #pragma unroll 8
    for (int d=0; d<32; ++d){
      float k0 = Ks[l*33+d];
      float k1 = Ks[(l+64)*33+d];
      float k2 = Ks[(l+128)*33+d];
      int m3c = (l<4)? (l+192) : 0;
      float k3 = (l<4)? Ks[m3c*33+d] : 0.f;
      #pragma unroll
      for (int i=0;i<4;i++){
        float qd = qs[(r0+i)*32+d];
        acc[i][0]+=qd*k0; acc[i][1]+=qd*k1; acc[i][2]+=qd*k2; acc[i][3]+=qd*k3;
      }
    }
    #pragma unroll
    for (int i=0;i<4;i++){
      int n = n0 + r0 + i;
      const float* rp = rpe + ((size_t)h*NPIX+n)*196;
      int m3c = (l<4)? (l+192) : 0;
      float r3 = rp[m3c];
      float s0=acc[i][0]*sc + rp[l];
      float s1=acc[i][1]*sc + rp[l+64];
      float s2=acc[i][2]*sc + rp[l+128];
      float s3=(l<4)? (acc[i][3]*sc + r3) : -1e30f;
      float mx = fmaxf(fmaxf(s0,s1),fmaxf(s2,s3));
      #pragma unroll
      for (int o=32;o>0;o>>=1) mx=fmaxf(mx,__shfl_xor(mx,o));
      s0=__expf(s0-mx); s1=__expf(s1-mx); s2=__expf(s2-mx); s3=(l<4)?__expf(s3-mx):0.f;
      float sum=s0+s1+s2+s3;
      #pragma unroll
      for (int o=32;o>0;o>>=1) sum+=__shfl_xor(sum,o);
      float inv=1.f/sum;
      Ss[(r0+i)*201 + l]      = s0*inv;
      Ss[(r0+i)*201 + l+64]   = s1*inv;
      Ss[(r0+i)*201 + l+128]  = s2*inv;
      if (l<4) Ss[(r0+i)*201 + l+192] = s3*inv;
    }
  }
  __syncthreads();

  // PV: output tile 64 rows x 32 d ; thread -> 4 rows x 2 d
  int d2=(tid&15)*2, rg=tid>>4;
  float o0[4][2];
  #pragma unroll
  for(int i=0;i<4;i++){ o0[i][0]=0; o0[i][1]=0; }
  #pragma unroll 4
  for (int m=0;m<196;m++){
    float v0=Vs[m*33+d2], v1=Vs[m*33+d2+1];
    #pragma unroll
    for(int i=0;i<4;i++){
      float p=Ss[(rg*4+i)*201+m];
      o0[i][0]+=p*v0; o0[i][1]+=p*v1;
    }
  }
  __syncthreads();   // Ss reads done; reuse Ss as [32][65] output tile
  #pragma unroll
  for(int i=0;i<4;i++){
    Ss[d2*65     + rg*4+i]=o0[i][0];
    Ss[(d2+1)*65 + rg*4+i]=o0[i][1];
  }
  __syncthreads();
  size_t base=((size_t)(b*128+64+h*32))*NPIX;
  for (int idx=tid; idx<2048; idx+=256){
    int d=idx>>6, r=idx&63;
    y[base + (size_t)d*NPIX + n0 + r] = Ss[d*65+r];
  }
}

// ---------------- K7: 3x3 depthwise p1 + bias + gelu + bn -> z1 ----------------
// grid: B*128, block: 256
__global__ void k_p1(const float* __restrict__ y, const float* __restrict__ p1_w,
                     const float* __restrict__ p1_b, const float* __restrict__ p1_g,
                     const float* __restrict__ p1_bb, float* __restrict__ z1){
  int c = blockIdx.x & 127;
  __shared__ float pl[NPIX];
  const float* yp = y + (size_t)blockIdx.x*NPIX;
  for (int p=threadIdx.x;p<NPIX;p+=256) pl[p]=yp[p];
  float w9[9];
  #pragma unroll
  for (int k=0;k<9;k++) w9[k]=p1_w[c*9+k];
  float bias=p1_b[c], g=p1_g[c], bb=p1_bb[c];
  __syncthreads();
  float* zp = z1 + (size_t)blockIdx.x*NPIX;
  for (int p=threadIdx.x;p<NPIX;p+=256){
    int h=p/56, w=p%56; float acc=bias;
    #pragma unroll
    for (int i=0;i<3;i++){ int hh=h+i-1; if((unsigned)hh<56u){
      #pragma unroll
      for(int j=0;j<3;j++){ int ww=w+j-1; if((unsigned)ww<56u) acc += pl[hh*56+ww]*w9[i*3+j]; } } }
    zp[p]=gelu_f(acc)*g+bb;
  }
}

// ---------------- K8: pointwise 128->16 + gelu + bn -> z2 ----------------
// grid: B*13, block: 256
__global__ void k_p2(const float* __restrict__ z1, const float* __restrict__ p2_w,
                     const float* __restrict__ p2_b, const float* __restrict__ p2_g,
                     const float* __restrict__ p2_bb, float* __restrict__ z2){
  int b=blockIdx.x/13, t=blockIdx.x%13; int n=t*256+threadIdx.x;
  if (n>=NPIX) return;
  const float* zp = z1 + (size_t)b*128*NPIX + n;
  float acc[16];
  #pragma unroll
  for (int i=0;i<16;i++) acc[i]=p2_b[i];
  #pragma unroll 4
  for (int c2=0;c2<128;c2++){
    float v = zp[(size_t)c2*NPIX];
    #pragma unroll
    for(int i=0;i<16;i++) acc[i]+=v*p2_w[i*128+c2];
  }
  float* op = z2 + (size_t)b*16*NPIX + n;
  #pragma unroll
  for(int i=0;i<16;i++) op[(size_t)i*NPIX] = gelu_f(acc[i])*p2_g[i]+p2_bb[i];
}

// ---------------- K9: pointwise 16->128 + bn + residual add y -> out ----------------
// grid: B*13, block: 256
__global__ void k_p3(const float* __restrict__ z2, const float* __restrict__ y,
                     const float* __restrict__ p3_w, const float* __restrict__ p3_b,
                     const float* __restrict__ p3_g, const float* __restrict__ p3_bb,
                     float* __restrict__ out){
  int b=blockIdx.x/13, t=blockIdx.x%13; int n=t*256+threadIdx.x;
  if (n>=NPIX) return;
  const float* zp = z2 + (size_t)b*16*NPIX + n;
  float zv[16];
  #pragma unroll
  for(int i=0;i<16;i++) zv[i]=zp[(size_t)i*NPIX];
  const float* yp = y + (size_t)b*128*NPIX + n;
  float* op = out + (size_t)b*128*NPIX + n;
  for (int o=0;o<128;o++){
    float acc=p3_b[o];
    #pragma unroll
    for(int i=0;i<16;i++) acc+=zv[i]*p3_w[o*16+i];
    op[(size_t)o*NPIX] = acc*p3_g[o]+p3_bb[o] + yp[(size_t)o*NPIX];
  }
}

// ---------------- launch ----------------
extern "C" void kernel_launch(void* const* d_in, const int* in_sizes, int n_in,
                              void* d_out, int out_size, void* d_ws, size_t ws_size,
                              hipStream_t stream) {
  (void)in_sizes; (void)n_in; (void)out_size; (void)ws_size;
  const float* x       = (const float*)d_in[0];
  const float* rpe     = (const float*)d_in[1];
  const float* dc_w    = (const float*)d_in[2];
  const float* dc_b    = (const float*)d_in[3];
  const float* dcp1_w  = (const float*)d_in[4];
  const float* dcp1_g  = (const float*)d_in[5];
  const float* dcp1_b  = (const float*)d_in[6];
  const float* dcp2_w  = (const float*)d_in[7];
  const float* dcp2_b  = (const float*)d_in[8];
  const float* q_w     = (const float*)d_in[9];
  const float* q_b     = (const float*)d_in[10];
  const float* kv_w    = (const float*)d_in[11];
  const float* kv_b    = (const float*)d_in[12];
  const float* sr1_w   = (const float*)d_in[13];
  const float* sr1_g   = (const float*)d_in[14];
  const float* sr1_b   = (const float*)d_in[15];
  const float* sr2_w   = (const float*)d_in[16];
  const float* sr2_g   = (const float*)d_in[17];
  const float* sr2_b   = (const float*)d_in[18];
  const float* lc_w    = (const float*)d_in[19];
  const float* lc_b    = (const float*)d_in[20];
  const float* p1_w    = (const float*)d_in[21];
  const float* p1_b    = (const float*)d_in[22];
  const float* p1_g    = (const float*)d_in[23];
  const float* p1_bb   = (const float*)d_in[24];
  const float* p2_w    = (const float*)d_in[25];
  const float* p2_b    = (const float*)d_in[26];
  const float* p2_g    = (const float*)d_in[27];
  const float* p2_bb   = (const float*)d_in[28];
  const float* p3_w    = (const float*)d_in[29];
  const float* p3_b    = (const float*)d_in[30];
  const float* p3_g    = (const float*)d_in[31];
  const float* p3_bb   = (const float*)d_in[32];
  float* out = (float*)d_out;
  float* ws  = (float*)d_ws;

  const size_t OFF_Y     = 0;           // 25,690,112 floats
  const size_t OFF_A     = 25690112;    // q (12.85M) then z1 (25.69M) — disjoint in time
  const size_t OFF_Z2    = 51380224;    // 3,211,264
  const size_t OFF_POOL  = 54591488;    // 36,864
  const size_t OFF_XMEAN = 54628352;    // 4,096
  const size_t OFF_W     = 54632448;    // 36,864
  const size_t OFF_DB    = 54669312;    // 4,096
  const size_t OFF_KV2   = 54673408;    // 802,816
  const size_t OFF_KV3   = 55476224;    // 802,816
  const size_t OFF_K     = 56279040;    // 802,816
  const size_t OFF_V     = 57081856;    // 802,816  (end = 57,884,672 floats = 231.5 MB)

  float* yb    = ws + OFF_Y;
  float* qbuf  = ws + OFF_A;
  float* z1    = ws + OFF_A;
  float* z2b   = ws + OFF_Z2;
  float* pool  = ws + OFF_POOL;
  float* xmean = ws + OFF_XMEAN;
  float* wgt   = ws + OFF_W;
  float* dbias = ws + OFF_DB;
  float* kv2   = ws + OFF_KV2;
  float* kv3   = ws + OFF_KV3;
  float* kws   = ws + OFF_K;
  float* vws   = ws + OFF_V;

  k_pool  <<<4096, 64, 0, stream>>>(x, pool, xmean);
  k_dcproj<<<64, 256, 0, stream>>>(pool, xmean, dcp1_w, dcp1_g, dcp1_b, dcp2_w, dcp2_b, dc_w, dc_b, wgt, dbias);
  k_y1    <<<4096, 256, 0, stream>>>(x, wgt, dbias, yb);
  k_qproj <<<3136, 256, 0, stream>>>(x, q_w, q_b, qbuf);
  k_sr    <<<4096, 256, 0, stream>>>(x, sr1_w, sr1_g, sr1_b, sr2_w, sr2_g, sr2_b, kv2);
  k_lc    <<<4096, 256, 0, stream>>>(kv2, lc_w, lc_b, kv3);
  k_kv    <<<64, 256, 0, stream>>>(kv3, kv_w, kv_b, kws, vws);
  k_attn  <<<6272, 256, 0, stream>>>(qbuf, kws, vws, rpe, yb);
  k_p1    <<<8192, 256, 0, stream>>>(yb, p1_w, p1_b, p1_g, p1_bb, z1);
  k_p2    <<<832, 256, 0, stream>>>(z1, p2_w, p2_b, p2_g, p2_bb, z2b);
  k_p3    <<<832, 256, 0, stream>>>(z2b, yb, p3_w, p3_b, p3_g, p3_bb, out);
}

// Round 2
// 671.893 us; speedup vs baseline: 1.8893x; 1.8893x over previous
//
#include <hip/hip_runtime.h>
#include <cstddef>

// Shapes: B=64, C=128, Ch=64, H=W=56, N=3136, G=2, K=3, heads=2, hd=32, Nk=196, inner=16
#define NPIX 3136

typedef __attribute__((ext_vector_type(8))) short bf16x8;
typedef __attribute__((ext_vector_type(4))) float f32x4;

__device__ __forceinline__ float gelu_f(float x){
  return 0.5f*x*(1.0f+erff(x*0.70710678118654752440f));
}

__device__ __forceinline__ unsigned pack_bf16(float a, float b){
  unsigned ua = __float_as_uint(a), ub = __float_as_uint(b);
  ua = (ua + 0x7FFFu + ((ua>>16)&1u)) >> 16;
  ub = (ub + 0x7FFFu + ((ub>>16)&1u)) >> 16;
  return ua | (ub<<16);
}

// ---------------- K1: adaptive_avg_pool(3x3, overlapping regions) + full mean ----------------
__global__ void k_pool(const float* __restrict__ x, float* __restrict__ pooled, float* __restrict__ xmean){
  int b = blockIdx.x >> 6, c = blockIdx.x & 63;
  const float* xp = x + ((size_t)(b*128 + c))*NPIX;
  float r[9] = {0,0,0,0,0,0,0,0,0};
  float tot = 0.f;
  for (int p = threadIdx.x; p < NPIX; p += 64){
    float v = xp[p];
    int h = p/56, w = p%56;
    tot += v;
    bool h0 = (h<=18), h1 = (h>=18 && h<=37), h2 = (h>=37);
    bool w0 = (w<=18), w1 = (w>=18 && w<=37), w2 = (w>=37);
    if(h0){ if(w0) r[0]+=v; if(w1) r[1]+=v; if(w2) r[2]+=v; }
    if(h1){ if(w0) r[3]+=v; if(w1) r[4]+=v; if(w2) r[5]+=v; }
    if(h2){ if(w0) r[6]+=v; if(w1) r[7]+=v; if(w2) r[8]+=v; }
  }
  #pragma unroll
  for (int o=32;o>0;o>>=1){
    #pragma unroll
    for (int k=0;k<9;k++) r[k]+=__shfl_xor(r[k],o);
    tot += __shfl_xor(tot,o);
  }
  if (threadIdx.x==0){
    const float cs[3]={19.f,20.f,19.f};
    #pragma unroll
    for(int i=0;i<3;i++)
      #pragma unroll
      for(int j=0;j<3;j++)
        pooled[(size_t)blockIdx.x*9 + i*3+j] = r[i*3+j]/(cs[i]*cs[j]);
    xmean[blockIdx.x] = tot*(1.f/3136.f);
  }
}

// ---------------- K2: dc_proj + softmax over G; build weight + dyn_bias ----
__global__ void k_dcproj(const float* __restrict__ pooled, const float* __restrict__ xmean,
    const float* __restrict__ dcp1_w, const float* __restrict__ dcp1_g, const float* __restrict__ dcp1_b,
    const float* __restrict__ dcp2_w, const float* __restrict__ dcp2_b,
    const float* __restrict__ dc_w, const float* __restrict__ dc_b,
    float* __restrict__ weightO, float* __restrict__ dyn_bias){
  int b = blockIdx.x; int tid = threadIdx.x;
  __shared__ float sp[576], sm[64], t1[144], t1b[16], s2[1152], s2b[128];
  for (int i=tid;i<576;i+=256) sp[i]=pooled[(size_t)b*576+i];
  if (tid<64) sm[tid]=xmean[b*64+tid];
  __syncthreads();
  for (int idx=tid; idx<160; idx+=256){
    if (idx<144){
      int o=idx/9, pos=idx%9; float s=0.f;
      for(int c2=0;c2<64;c2++) s += sp[c2*9+pos]*dcp1_w[o*64+c2];
      t1[idx]=gelu_f(s*dcp1_g[o]+dcp1_b[o]);
    } else {
      int o=idx-144; float s=0.f;
      for(int c2=0;c2<64;c2++) s+=sm[c2]*dcp1_w[o*64+c2];
      t1b[o]=gelu_f(s*dcp1_g[o]+dcp1_b[o]);
    }
  }
  __syncthreads();
  for (int idx=tid; idx<1280; idx+=256){
    if (idx<1152){
      int o=idx/9,pos=idx%9; float s=dcp2_b[o];
      #pragma unroll
      for(int i=0;i<16;i++) s+=t1[i*9+pos]*dcp2_w[o*16+i];
      s2[idx]=s;
    } else {
      int o=idx-1152; float s=dcp2_b[o];
      #pragma unroll
      for(int i=0;i<16;i++) s+=t1b[i]*dcp2_w[o*16+i];
      s2b[o]=s;
    }
  }
  __syncthreads();
  for (int idx=tid; idx<640; idx+=256){
    if (idx<576){
      int ch=idx/9, pos=idx%9;
      float a=s2[ch*9+pos], bb=s2[(64+ch)*9+pos];
      float m=fmaxf(a,bb); float e0=expf(a-m), e1=expf(bb-m); float w0=e0/(e0+e1);
      weightO[(size_t)b*576+idx] = w0*dc_w[ch*9+pos] + (1.f-w0)*dc_w[576+ch*9+pos];
    } else {
      int ch=idx-576;
      float a=s2b[ch], bb=s2b[64+ch];
      float m=fmaxf(a,bb); float e0=expf(a-m), e1=expf(bb-m); float w0=e0/(e0+e1);
      dyn_bias[b*64+ch] = w0*dc_b[ch] + (1.f-w0)*dc_b[64+ch];
    }
  }
}

// ---------------- K3: dynamic depthwise 3x3 conv on x1 -> y[:, :64] ----------------
__global__ void k_y1(const float* __restrict__ x, const float* __restrict__ weightO,
                     const float* __restrict__ dyn_bias, float* __restrict__ y){
  int b = blockIdx.x>>6, c = blockIdx.x&63;
  __shared__ float pl[NPIX];
  const float* xp = x + ((size_t)(b*128+c))*NPIX;
  for (int p=threadIdx.x;p<NPIX;p+=256) pl[p]=xp[p];
  float w9[9];
  #pragma unroll
  for (int k=0;k<9;k++) w9[k]=weightO[(size_t)blockIdx.x*9+k];
  float bias = dyn_bias[blockIdx.x];
  __syncthreads();
  float* yp = y + ((size_t)(b*128+c))*NPIX;
  for (int p=threadIdx.x;p<NPIX;p+=256){
    int h=p/56, w=p%56;
    float acc=bias;
    #pragma unroll
    for (int i=0;i<3;i++){ int hh=h+i-1; if((unsigned)hh<56u){
      #pragma unroll
      for(int j=0;j<3;j++){ int ww=w+j-1; if((unsigned)ww<56u) acc += pl[hh*56+ww]*w9[i*3+j]; } } }
    yp[p]=acc;
  }
}

// ---------------- K4: q projection ----------------
__global__ void k_qproj(const float* __restrict__ x, const float* __restrict__ q_w,
                        const float* __restrict__ q_b, float* __restrict__ q){
  int b = blockIdx.x/49, t = blockIdx.x%49; int n0 = t*64; int tid = threadIdx.x;
  __shared__ float qwT[64*64]; // [c][o]
  __shared__ float xt[64*64];  // [c][p]
  for (int idx=tid; idx<4096; idx+=256){ int o=idx>>6, c2=idx&63; qwT[c2*64+o]=q_w[idx]; }
  for (int idx=tid; idx<4096; idx+=256){ int c2=idx>>6, p=idx&63;
    xt[idx]= x[((size_t)(b*128+64+c2))*NPIX + n0+p]; }
  __syncthreads();
  int od = tid&63;
  float qb = q_b[od];
  for (int p = tid>>6; p<64; p+=4){
    float acc=qb;
    #pragma unroll 8
    for (int c2=0;c2<64;c2++) acc += xt[c2*64+p]*qwT[c2*64+od];
    q[(((size_t)(b*2+(od>>5)))*NPIX + n0+p)*32 + (od&31)] = acc;
  }
}

// ---------------- K5a: 7x7 s4 p3 depthwise + BN/GELU + sr2 BN -> kv2 ----------------
__global__ void k_sr(const float* __restrict__ x, const float* __restrict__ sr1_w,
                     const float* __restrict__ sr1_g, const float* __restrict__ sr1_b,
                     const float* __restrict__ sr2_w, const float* __restrict__ sr2_g,
                     const float* __restrict__ sr2_b, float* __restrict__ kv2){
  int b=blockIdx.x>>6, c=blockIdx.x&63;
  __shared__ float pl[NPIX];
  const float* xp = x + ((size_t)(b*128+64+c))*NPIX;
  for (int p=threadIdx.x;p<NPIX;p+=256) pl[p]=xp[p];
  __syncthreads();
  int t=threadIdx.x;
  if (t<196){
    int oy=t/14, ox=t%14;
    float acc=0.f;
    #pragma unroll
    for(int i=0;i<7;i++){ int yy=oy*4-3+i; if((unsigned)yy<56u){
      #pragma unroll
      for(int j=0;j<7;j++){ int xx=ox*4-3+j; if((unsigned)xx<56u) acc += pl[yy*56+xx]*sr1_w[c*49+i*7+j]; } } }
    float g = gelu_f(acc*sr1_g[c]+sr1_b[c]);
    kv2[(size_t)blockIdx.x*196+t] = (g*sr2_w[c])*sr2_g[c]+sr2_b[c];
  }
}

// ---------------- K5b: 3x3 depthwise residual on kv2 -> kv3 ----------------
__global__ void k_lc(const float* __restrict__ kv2, const float* __restrict__ lc_w,
                     const float* __restrict__ lc_b, float* __restrict__ kv3){
  int c=blockIdx.x&63;
  __shared__ float pl[196];
  for (int p=threadIdx.x;p<196;p+=256) pl[p]=kv2[(size_t)blockIdx.x*196+p];
  __syncthreads();
  int t=threadIdx.x;
  if (t<196){
    int oy=t/14, ox=t%14; float acc=lc_b[c]+pl[t];
    #pragma unroll
    for(int i=0;i<3;i++){int yy=oy+i-1; if((unsigned)yy<14u){
      #pragma unroll
      for(int j=0;j<3;j++){int xx=ox+j-1; if((unsigned)xx<14u) acc+=pl[yy*14+xx]*lc_w[c*9+i*3+j];}}}
    kv3[(size_t)blockIdx.x*196+t]=acc;
  }
}

// ---------------- K5c: kv pointwise 64->128, split K/V in [m][d] layout ----------------
__global__ void k_kv(const float* __restrict__ kv3, const float* __restrict__ kv_w,
                     const float* __restrict__ kv_b, float* __restrict__ kws, float* __restrict__ vws){
  int b=blockIdx.x; int tid=threadIdx.x;
  __shared__ float s[64*196];
  for (int i=tid;i<12544;i+=256) s[i]=kv3[(size_t)b*12544+i];
  __syncthreads();
  for (int idx=tid; idx<128*196; idx+=256){
    int o=idx/196, m=idx%196;
    float acc=kv_b[o];
    #pragma unroll 8
    for(int c2=0;c2<64;c2++) acc += s[c2*196+m]*kv_w[o*64+c2];
    int h=(o>>5)&1, d=o&31;
    if (o<64) kws[(((size_t)(b*2+h))*196+m)*32+d] = acc;
    else      vws[(((size_t)(b*2+h))*196+m)*32+d] = acc;
  }
}

// ---------------- K6: MFMA attention ----------------
// grid: 49*128 (tile-major), block 256 (4 waves); each block: one (bh), 64 q-rows.
// QK^T: A=Q[16,32], B=K^T[32,16] via 13 MFMAs (m padded 196->208, rpe*sqrt(32) as C-init).
// Softmax in D-layout regs (col=lane&15, row=4*(lane>>4)+r; reduce via shfl_xor 1/2/4/8).
// P -> bf16 pairs -> per-wave LDS [16][232-stride]; PV: A=P, B=Vb prepacked frag layout.
__global__ __launch_bounds__(256,2) void k_attn(const float* __restrict__ q, const float* __restrict__ kws,
                       const float* __restrict__ vws, const float* __restrict__ rpe,
                       float* __restrict__ y){
  __shared__ unsigned Ks32[208*20];     // K bf16 [208 m][40-stride d]   16640 B
  __shared__ unsigned Vb32[2*7*64*4];   // V B-frag packed               14336 B
  __shared__ unsigned Qs32[64*20];      // Q bf16 [64 r][40-stride d]     5120 B
  __shared__ unsigned Ps32[4*16*116];   // per-wave P bf16 [16][232]     29696 B
  __shared__ float Os[64*33];           // output tile                    8448 B
  int bh = blockIdx.x & 127, tile = blockIdx.x >> 7;
  int b=bh>>1, h=bh&1, n0=tile*64, tid=threadIdx.x;
  const float* kp = kws + (size_t)bh*6272;
  const float* vp = vws + (size_t)bh*6272;
  // stage K (bf16 pairs)
  for (int i=tid;i<208*16;i+=256){ int m=i>>4, d2=(i&15)<<1;
    float v0=0.f, v1=0.f; if(m<196){ v0=kp[m*32+d2]; v1=kp[m*32+d2+1]; }
    Ks32[m*20+(i&15)] = pack_bf16(v0,v1); }
  // stage V in B-fragment layout: Vb[(dh*7+s)*64+lane][ip] = pack(V[m0][d],V[m0+1][d])
  for (int j=tid;j<3584;j+=256){
    int ip=j&3; int t=j>>2; int lane=t&63; int u=t>>6; int s=u%7, dh=u/7;
    int m0 = s*32 + ((lane>>4)<<3) + ip*2; int d = dh*16 + (lane&15);
    float v0 = (m0<196)? vp[m0*32+d] : 0.f;
    float v1 = (m0+1<196)? vp[(m0+1)*32+d] : 0.f;
    Vb32[j] = pack_bf16(v0,v1);
  }
  // stage Q
  const float* qp = q + ((size_t)bh*NPIX + n0)*32;
  for (int i=tid;i<1024;i+=256){ int r=i>>4, d2=(i&15)<<1;
    Qs32[r*20+(i&15)] = pack_bf16(qp[r*32+d2], qp[r*32+d2+1]); }
  // zero P pad cols (m 208..223)
  for (int i=tid;i<512;i+=256){ int w=i>>7, row=(i>>3)&15, cc=i&7;
    Ps32[w*1856 + row*116 + 104 + cc] = 0; }
  __syncthreads();

  int wv = tid>>6, l = tid&63, g = l>>4, c = l&15, qr = wv*16;
  const short* QsS = (const short*)Qs32;
  const short* KsS = (const short*)Ks32;
  bf16x8 qa = *(const bf16x8*)(QsS + (qr+c)*40 + 8*g);

  const float inv_sc = 5.656854249492381f;  // sqrt(32)
  const float sc     = 0.17677669529663687f;
  const float* rp = rpe + ((size_t)(h*NPIX + n0 + qr))*196;
  f32x4 acc[13];
  #pragma unroll
  for (int mt=0; mt<12; mt++){
    #pragma unroll
    for (int r=0;r<4;r++) acc[mt][r] = rp[(size_t)(4*g+r)*196 + mt*16 + c] * inv_sc;
  }
  {
    bool v = (c<4);
    #pragma unroll
    for (int r=0;r<4;r++) acc[12][r] = v ? rp[(size_t)(4*g+r)*196 + 192 + c]*inv_sc : 0.f;
  }
  #pragma unroll
  for (int mt=0; mt<13; mt++){
    bf16x8 kb = *(const bf16x8*)(KsS + (mt*16 + c)*40 + 8*g);
    acc[mt] = __builtin_amdgcn_mfma_f32_16x16x32_bf16(qa, kb, acc[mt], 0,0,0);
  }
  // scores
  #pragma unroll
  for (int mt=0;mt<13;mt++){
    #pragma unroll
    for (int r=0;r<4;r++) acc[mt][r] *= sc;
  }
  if (c>=4){
    #pragma unroll
    for (int r=0;r<4;r++) acc[12][r] = -1e30f;
  }
  // softmax per row
  #pragma unroll
  for (int r=0;r<4;r++){
    float mx = acc[0][r];
    #pragma unroll
    for (int mt=1;mt<13;mt++) mx = fmaxf(mx, acc[mt][r]);
    #pragma unroll
    for (int o=1;o<16;o<<=1) mx = fmaxf(mx, __shfl_xor(mx,o));
    float sm = 0.f;
    #pragma unroll
    for (int mt=0;mt<13;mt++){ float e = __expf(acc[mt][r]-mx); acc[mt][r]=e; sm += e; }
    #pragma unroll
    for (int o=1;o<16;o<<=1) sm += __shfl_xor(sm,o);
    float inv = 1.f/sm;
    #pragma unroll
    for (int mt=0;mt<13;mt++) acc[mt][r] *= inv;
  }
  // write P bf16 (pair lanes via shfl to pack dwords)
  unsigned* Pw = Ps32 + wv*1856;
  #pragma unroll
  for (int mt=0;mt<13;mt++){
    #pragma unroll
    for (int r=0;r<4;r++){
      float other = __shfl_xor(acc[mt][r], 1);
      if ((l&1)==0) Pw[(4*g+r)*116 + mt*8 + (c>>1)] = pack_bf16(acc[mt][r], other);
    }
  }
  // PV
  const short* PsS = (const short*)Pw;
  const short* VbS = (const short*)Vb32;
  f32x4 o0 = {0.f,0.f,0.f,0.f}, o1 = {0.f,0.f,0.f,0.f};
  #pragma unroll
  for (int s=0;s<7;s++){
    bf16x8 pa = *(const bf16x8*)(PsS + c*232 + s*32 + 8*g);
    bf16x8 v0 = *(const bf16x8*)(VbS + (s*64 + l)*8);
    bf16x8 v1 = *(const bf16x8*)(VbS + ((7+s)*64 + l)*8);
    o0 = __builtin_amdgcn_mfma_f32_16x16x32_bf16(pa, v0, o0, 0,0,0);
    o1 = __builtin_amdgcn_mfma_f32_16x16x32_bf16(pa, v1, o1, 0,0,0);
  }
  #pragma unroll
  for (int r=0;r<4;r++){
    Os[(qr + 4*g + r)*33 + c]      = o0[r];
    Os[(qr + 4*g + r)*33 + 16 + c] = o1[r];
  }
  __syncthreads();
  size_t base = ((size_t)(b*128 + 64 + h*32))*NPIX;
  for (int i=tid;i<2048;i+=256){ int d=i>>6, rr=i&63;
    y[base + (size_t)d*NPIX + n0 + rr] = Os[rr*33 + d]; }
}

// ---------------- K7: 3x3 depthwise p1 + bias + gelu + bn -> z1 ----------------
__global__ void k_p1(const float* __restrict__ y, const float* __restrict__ p1_w,
                     const float* __restrict__ p1_b, const float* __restrict__ p1_g,
                     const float* __restrict__ p1_bb, float* __restrict__ z1){
  int c = blockIdx.x & 127;
  __shared__ float pl[NPIX];
  const float* yp = y + (size_t)blockIdx.x*NPIX;
  for (int p=threadIdx.x;p<NPIX;p+=256) pl[p]=yp[p];
  float w9[9];
  #pragma unroll
  for (int k=0;k<9;k++) w9[k]=p1_w[c*9+k];
  float bias=p1_b[c], g=p1_g[c], bb=p1_bb[c];
  __syncthreads();
  float* zp = z1 + (size_t)blockIdx.x*NPIX;
  for (int p=threadIdx.x;p<NPIX;p+=256){
    int h=p/56, w=p%56; float acc=bias;
    #pragma unroll
    for (int i=0;i<3;i++){ int hh=h+i-1; if((unsigned)hh<56u){
      #pragma unroll
      for(int j=0;j<3;j++){ int ww=w+j-1; if((unsigned)ww<56u) acc += pl[hh*56+ww]*w9[i*3+j]; } } }
    zp[p]=gelu_f(acc)*g+bb;
  }
}

// ---------------- K8: pointwise 128->16 + gelu + bn -> z2 ----------------
__global__ void k_p2(const float* __restrict__ z1, const float* __restrict__ p2_w,
                     const float* __restrict__ p2_b, const float* __restrict__ p2_g,
                     const float* __restrict__ p2_bb, float* __restrict__ z2){
  int b=blockIdx.x/13, t=blockIdx.x%13; int n=t*256+threadIdx.x;
  if (n>=NPIX) return;
  const float* zp = z1 + (size_t)b*128*NPIX + n;
  float acc[16];
  #pragma unroll
  for (int i=0;i<16;i++) acc[i]=p2_b[i];
  #pragma unroll 4
  for (int c2=0;c2<128;c2++){
    float v = zp[(size_t)c2*NPIX];
    #pragma unroll
    for(int i=0;i<16;i++) acc[i]+=v*p2_w[i*128+c2];
  }
  float* op = z2 + (size_t)b*16*NPIX + n;
  #pragma unroll
  for(int i=0;i<16;i++) op[(size_t)i*NPIX] = gelu_f(acc[i])*p2_g[i]+p2_bb[i];
}

// ---------------- K9: pointwise 16->128 + bn + residual add y -> out ----------------
__global__ void k_p3(const float* __restrict__ z2, const float* __restrict__ y,
                     const float* __restrict__ p3_w, const float* __restrict__ p3_b,
                     const float* __restrict__ p3_g, const float* __restrict__ p3_bb,
                     float* __restrict__ out){
  int b=blockIdx.x/13, t=blockIdx.x%13; int n=t*256+threadIdx.x;
  if (n>=NPIX) return;
  const float* zp = z2 + (size_t)b*16*NPIX + n;
  float zv[16];
  #pragma unroll
  for(int i=0;i<16;i++) zv[i]=zp[(size_t)i*NPIX];
  const float* yp = y + (size_t)b*128*NPIX + n;
  float* op = out + (size_t)b*128*NPIX + n;
  for (int o=0;o<128;o++){
    float acc=p3_b[o];
    #pragma unroll
    for(int i=0;i<16;i++) acc+=zv[i]*p3_w[o*16+i];
    op[(size_t)o*NPIX] = acc*p3_g[o]+p3_bb[o] + yp[(size_t)o*NPIX];
  }
}

// ---------------- launch ----------------
extern "C" void kernel_launch(void* const* d_in, const int* in_sizes, int n_in,
                              void* d_out, int out_size, void* d_ws, size_t ws_size,
                              hipStream_t stream) {
  (void)in_sizes; (void)n_in; (void)out_size; (void)ws_size;
  const float* x       = (const float*)d_in[0];
  const float* rpe     = (const float*)d_in[1];
  const float* dc_w    = (const float*)d_in[2];
  const float* dc_b    = (const float*)d_in[3];
  const float* dcp1_w  = (const float*)d_in[4];
  const float* dcp1_g  = (const float*)d_in[5];
  const float* dcp1_b  = (const float*)d_in[6];
  const float* dcp2_w  = (const float*)d_in[7];
  const float* dcp2_b  = (const float*)d_in[8];
  const float* q_w     = (const float*)d_in[9];
  const float* q_b     = (const float*)d_in[10];
  const float* kv_w    = (const float*)d_in[11];
  const float* kv_b    = (const float*)d_in[12];
  const float* sr1_w   = (const float*)d_in[13];
  const float* sr1_g   = (const float*)d_in[14];
  const float* sr1_b   = (const float*)d_in[15];
  const float* sr2_w   = (const float*)d_in[16];
  const float* sr2_g   = (const float*)d_in[17];
  const float* sr2_b   = (const float*)d_in[18];
  const float* lc_w    = (const float*)d_in[19];
  const float* lc_b    = (const float*)d_in[20];
  const float* p1_w    = (const float*)d_in[21];
  const float* p1_b    = (const float*)d_in[22];
  const float* p1_g    = (const float*)d_in[23];
  const float* p1_bb   = (const float*)d_in[24];
  const float* p2_w    = (const float*)d_in[25];
  const float* p2_b    = (const float*)d_in[26];
  const float* p2_g    = (const float*)d_in[27];
  const float* p2_bb   = (const float*)d_in[28];
  const float* p3_w    = (const float*)d_in[29];
  const float* p3_b    = (const float*)d_in[30];
  const float* p3_g    = (const float*)d_in[31];
  const float* p3_bb   = (const float*)d_in[32];
  float* out = (float*)d_out;
  float* ws  = (float*)d_ws;

  const size_t OFF_Y     = 0;
  const size_t OFF_A     = 25690112;
  const size_t OFF_Z2    = 51380224;
  const size_t OFF_POOL  = 54591488;
  const size_t OFF_XMEAN = 54628352;
  const size_t OFF_W     = 54632448;
  const size_t OFF_DB    = 54669312;
  const size_t OFF_KV2   = 54673408;
  const size_t OFF_KV3   = 55476224;
  const size_t OFF_K     = 56279040;
  const size_t OFF_V     = 57081856;

  float* yb    = ws + OFF_Y;
  float* qbuf  = ws + OFF_A;
  float* z1    = ws + OFF_A;
  float* z2b   = ws + OFF_Z2;
  float* pool  = ws + OFF_POOL;
  float* xmean = ws + OFF_XMEAN;
  float* wgt   = ws + OFF_W;
  float* dbias = ws + OFF_DB;
  float* kv2   = ws + OFF_KV2;
  float* kv3   = ws + OFF_KV3;
  float* kws   = ws + OFF_K;
  float* vws   = ws + OFF_V;

  k_pool  <<<4096, 64, 0, stream>>>(x, pool, xmean);
  k_dcproj<<<64, 256, 0, stream>>>(pool, xmean, dcp1_w, dcp1_g, dcp1_b, dcp2_w, dcp2_b, dc_w, dc_b, wgt, dbias);
  k_y1    <<<4096, 256, 0, stream>>>(x, wgt, dbias, yb);
  k_qproj <<<3136, 256, 0, stream>>>(x, q_w, q_b, qbuf);
  k_sr    <<<4096, 256, 0, stream>>>(x, sr1_w, sr1_g, sr1_b, sr2_w, sr2_g, sr2_b, kv2);
  k_lc    <<<4096, 256, 0, stream>>>(kv2, lc_w, lc_b, kv3);
  k_kv    <<<64, 256, 0, stream>>>(kv3, kv_w, kv_b, kws, vws);
  k_attn  <<<6272, 256, 0, stream>>>(qbuf, kws, vws, rpe, yb);
  k_p1    <<<8192, 256, 0, stream>>>(yb, p1_w, p1_b, p1_g, p1_bb, z1);
  k_p2    <<<832, 256, 0, stream>>>(z1, p2_w, p2_b, p2_g, p2_bb, z2b);
  k_p3    <<<832, 256, 0, stream>>>(z2b, yb, p3_w, p3_b, p3_g, p3_bb, out);
}

// Round 3
// 439.569 us; speedup vs baseline: 2.8878x; 1.5285x over previous
//
#include <hip/hip_runtime.h>
#include <cstddef>

// Shapes: B=64, C=128, Ch=64, H=W=56, N=3136, G=2, K=3, heads=2, hd=32, Nk=196, inner=16
#define NPIX 3136

typedef __attribute__((ext_vector_type(8))) short bf16x8;
typedef __attribute__((ext_vector_type(4))) float f32x4;

__device__ __forceinline__ float gelu_f(float x){
  return 0.5f*x*(1.0f+erff(x*0.70710678118654752440f));
}

__device__ __forceinline__ unsigned pack_bf16(float a, float b){
  unsigned ua = __float_as_uint(a), ub = __float_as_uint(b);
  ua = (ua + 0x7FFFu + ((ua>>16)&1u)) >> 16;
  ub = (ub + 0x7FFFu + ((ub>>16)&1u)) >> 16;
  return ua | (ub<<16);
}

// ---------------- K1: adaptive_avg_pool(3x3, overlapping regions) + full mean ----------------
__global__ void k_pool(const float* __restrict__ x, float* __restrict__ pooled, float* __restrict__ xmean){
  int b = blockIdx.x >> 6, c = blockIdx.x & 63;
  const float* xp = x + ((size_t)(b*128 + c))*NPIX;
  float r[9] = {0,0,0,0,0,0,0,0,0};
  float tot = 0.f;
  for (int p = threadIdx.x; p < NPIX; p += 64){
    float v = xp[p];
    int h = p/56, w = p%56;
    tot += v;
    bool h0 = (h<=18), h1 = (h>=18 && h<=37), h2 = (h>=37);
    bool w0 = (w<=18), w1 = (w>=18 && w<=37), w2 = (w>=37);
    if(h0){ if(w0) r[0]+=v; if(w1) r[1]+=v; if(w2) r[2]+=v; }
    if(h1){ if(w0) r[3]+=v; if(w1) r[4]+=v; if(w2) r[5]+=v; }
    if(h2){ if(w0) r[6]+=v; if(w1) r[7]+=v; if(w2) r[8]+=v; }
  }
  #pragma unroll
  for (int o=32;o>0;o>>=1){
    #pragma unroll
    for (int k=0;k<9;k++) r[k]+=__shfl_xor(r[k],o);
    tot += __shfl_xor(tot,o);
  }
  if (threadIdx.x==0){
    const float cs[3]={19.f,20.f,19.f};
    #pragma unroll
    for(int i=0;i<3;i++)
      #pragma unroll
      for(int j=0;j<3;j++)
        pooled[(size_t)blockIdx.x*9 + i*3+j] = r[i*3+j]/(cs[i]*cs[j]);
    xmean[blockIdx.x] = tot*(1.f/3136.f);
  }
}

// ---------------- K2: dc_proj + softmax over G; build weight + dyn_bias ----
__global__ void k_dcproj(const float* __restrict__ pooled, const float* __restrict__ xmean,
    const float* __restrict__ dcp1_w, const float* __restrict__ dcp1_g, const float* __restrict__ dcp1_b,
    const float* __restrict__ dcp2_w, const float* __restrict__ dcp2_b,
    const float* __restrict__ dc_w, const float* __restrict__ dc_b,
    float* __restrict__ weightO, float* __restrict__ dyn_bias){
  int b = blockIdx.x; int tid = threadIdx.x;
  __shared__ float sp[576], sm[64], t1[144], t1b[16], s2[1152], s2b[128];
  for (int i=tid;i<576;i+=256) sp[i]=pooled[(size_t)b*576+i];
  if (tid<64) sm[tid]=xmean[b*64+tid];
  __syncthreads();
  for (int idx=tid; idx<160; idx+=256){
    if (idx<144){
      int o=idx/9, pos=idx%9; float s=0.f;
      for(int c2=0;c2<64;c2++) s += sp[c2*9+pos]*dcp1_w[o*64+c2];
      t1[idx]=gelu_f(s*dcp1_g[o]+dcp1_b[o]);
    } else {
      int o=idx-144; float s=0.f;
      for(int c2=0;c2<64;c2++) s+=sm[c2]*dcp1_w[o*64+c2];
      t1b[o]=gelu_f(s*dcp1_g[o]+dcp1_b[o]);
    }
  }
  __syncthreads();
  for (int idx=tid; idx<1280; idx+=256){
    if (idx<1152){
      int o=idx/9,pos=idx%9; float s=dcp2_b[o];
      #pragma unroll
      for(int i=0;i<16;i++) s+=t1[i*9+pos]*dcp2_w[o*16+i];
      s2[idx]=s;
    } else {
      int o=idx-1152; float s=dcp2_b[o];
      #pragma unroll
      for(int i=0;i<16;i++) s+=t1b[i]*dcp2_w[o*16+i];
      s2b[o]=s;
    }
  }
  __syncthreads();
  for (int idx=tid; idx<640; idx+=256){
    if (idx<576){
      int ch=idx/9, pos=idx%9;
      float a=s2[ch*9+pos], bb=s2[(64+ch)*9+pos];
      float m=fmaxf(a,bb); float e0=expf(a-m), e1=expf(bb-m); float w0=e0/(e0+e1);
      weightO[(size_t)b*576+idx] = w0*dc_w[ch*9+pos] + (1.f-w0)*dc_w[576+ch*9+pos];
    } else {
      int ch=idx-576;
      float a=s2b[ch], bb=s2b[64+ch];
      float m=fmaxf(a,bb); float e0=expf(a-m), e1=expf(bb-m); float w0=e0/(e0+e1);
      dyn_bias[b*64+ch] = w0*dc_b[ch] + (1.f-w0)*dc_b[64+ch];
    }
  }
}

// ---------------- K3: dynamic depthwise 3x3 conv on x1 -> y[:, :64] ----------------
__global__ void k_y1(const float* __restrict__ x, const float* __restrict__ weightO,
                     const float* __restrict__ dyn_bias, float* __restrict__ y){
  int b = blockIdx.x>>6, c = blockIdx.x&63;
  __shared__ float pl[NPIX];
  const float* xp = x + ((size_t)(b*128+c))*NPIX;
  for (int p=threadIdx.x;p<NPIX;p+=256) pl[p]=xp[p];
  float w9[9];
  #pragma unroll
  for (int k=0;k<9;k++) w9[k]=weightO[(size_t)blockIdx.x*9+k];
  float bias = dyn_bias[blockIdx.x];
  __syncthreads();
  float* yp = y + ((size_t)(b*128+c))*NPIX;
  for (int p=threadIdx.x;p<NPIX;p+=256){
    int h=p/56, w=p%56;
    float acc=bias;
    #pragma unroll
    for (int i=0;i<3;i++){ int hh=h+i-1; if((unsigned)hh<56u){
      #pragma unroll
      for(int j=0;j<3;j++){ int ww=w+j-1; if((unsigned)ww<56u) acc += pl[hh*56+ww]*w9[i*3+j]; } } }
    yp[p]=acc;
  }
}

// ---------------- K4: q projection -> packed bf16 rows qbf[(bh*3136+n)*16 + d2] ----------------
__global__ void k_qproj(const float* __restrict__ x, const float* __restrict__ q_w,
                        const float* __restrict__ q_b, unsigned* __restrict__ qbf){
  int b = blockIdx.x/49, t = blockIdx.x%49; int n0 = t*64; int tid = threadIdx.x;
  __shared__ float qwT[64*64]; // [c][o]
  __shared__ float xt[64*64];  // [c][p]
  for (int idx=tid; idx<4096; idx+=256){ int o=idx>>6, c2=idx&63; qwT[c2*64+o]=q_w[idx]; }
  for (int idx=tid; idx<4096; idx+=256){ int c2=idx>>6, p=idx&63;
    xt[idx]= x[((size_t)(b*128+64+c2))*NPIX + n0+p]; }
  __syncthreads();
  int d2_ = tid&31, prow = tid>>5;         // o pair (2d2_, 2d2_+1), 8 pixels
  int o0 = 2*d2_; int h = d2_>>4, dd = d2_&15;
  float b0 = q_b[o0], b1 = q_b[o0+1];
  float a0[8], a1[8];
  #pragma unroll
  for (int i=0;i<8;i++){ a0[i]=b0; a1[i]=b1; }
  #pragma unroll 4
  for (int c2=0;c2<64;c2++){
    float w0 = qwT[c2*64+o0], w1 = qwT[c2*64+o0+1];
    #pragma unroll
    for (int i=0;i<8;i++){ float xv = xt[c2*64 + prow*8 + i]; a0[i]+=xv*w0; a1[i]+=xv*w1; }
  }
  #pragma unroll
  for (int i=0;i<8;i++)
    qbf[((size_t)(b*2+h)*NPIX + n0 + prow*8 + i)*16 + dd] = pack_bf16(a0[i], a1[i]);
}

// ---------------- K5a: 7x7 s4 p3 depthwise + BN/GELU + sr2 BN -> kv2 ----------------
__global__ void k_sr(const float* __restrict__ x, const float* __restrict__ sr1_w,
                     const float* __restrict__ sr1_g, const float* __restrict__ sr1_b,
                     const float* __restrict__ sr2_w, const float* __restrict__ sr2_g,
                     const float* __restrict__ sr2_b, float* __restrict__ kv2){
  int b=blockIdx.x>>6, c=blockIdx.x&63;
  __shared__ float pl[NPIX];
  const float* xp = x + ((size_t)(b*128+64+c))*NPIX;
  for (int p=threadIdx.x;p<NPIX;p+=256) pl[p]=xp[p];
  __syncthreads();
  int t=threadIdx.x;
  if (t<196){
    int oy=t/14, ox=t%14;
    float acc=0.f;
    #pragma unroll
    for(int i=0;i<7;i++){ int yy=oy*4-3+i; if((unsigned)yy<56u){
      #pragma unroll
      for(int j=0;j<7;j++){ int xx=ox*4-3+j; if((unsigned)xx<56u) acc += pl[yy*56+xx]*sr1_w[c*49+i*7+j]; } } }
    float g = gelu_f(acc*sr1_g[c]+sr1_b[c]);
    kv2[(size_t)blockIdx.x*196+t] = (g*sr2_w[c])*sr2_g[c]+sr2_b[c];
  }
}

// ---------------- K5b: 3x3 depthwise residual on kv2 -> kv3 ----------------
__global__ void k_lc(const float* __restrict__ kv2, const float* __restrict__ lc_w,
                     const float* __restrict__ lc_b, float* __restrict__ kv3){
  int c=blockIdx.x&63;
  __shared__ float pl[196];
  for (int p=threadIdx.x;p<196;p+=256) pl[p]=kv2[(size_t)blockIdx.x*196+p];
  __syncthreads();
  int t=threadIdx.x;
  if (t<196){
    int oy=t/14, ox=t%14; float acc=lc_b[c]+pl[t];
    #pragma unroll
    for(int i=0;i<3;i++){int yy=oy+i-1; if((unsigned)yy<14u){
      #pragma unroll
      for(int j=0;j<3;j++){int xx=ox+j-1; if((unsigned)xx<14u) acc+=pl[yy*14+xx]*lc_w[c*9+i*3+j];}}}
    kv3[(size_t)blockIdx.x*196+t]=acc;
  }
}

// ---------------- K5c: kv pointwise 64->128, emit K rows (bf16 pairs) + V B-fragments --------
// grid: 128 (b * {K,V}), block 256
__global__ void k_kv(const float* __restrict__ kv3, const float* __restrict__ kv_w,
                     const float* __restrict__ kv_b, unsigned* __restrict__ kbf,
                     unsigned* __restrict__ vbf){
  int b = blockIdx.x>>1, half = blockIdx.x&1; int tid=threadIdx.x;
  __shared__ float s[64*196];
  for (int i=tid;i<12544;i+=256) s[i]=kv3[(size_t)b*12544+i];
  __syncthreads();
  if (half==0){
    // K: o in [0,64) paired over d; kbf[(bh*208+m)*16 + d2] = pack(K[m][2d2],K[m][2d2+1])
    for (int idx=tid; idx<6272; idx+=256){
      int m = idx>>5, o2 = idx&31; int o = 2*o2;
      float acc0=kv_b[o], acc1=kv_b[o+1];
      #pragma unroll 8
      for (int c2=0;c2<64;c2++){ float v=s[c2*196+m]; acc0+=v*kv_w[o*64+c2]; acc1+=v*kv_w[(o+1)*64+c2]; }
      int h=o2>>4, d2=o2&15;
      kbf[((size_t)(b*2+h)*208 + m)*16 + d2] = pack_bf16(acc0, acc1);
    }
    // zero pad rows m=196..207
    for (int i=tid;i<384;i+=256){ int h=i/192, r=i%192, m=196+(r>>4), d2=r&15;
      kbf[((size_t)(b*2+h)*208 + m)*16 + d2] = 0; }
  } else {
    // V: o in [64,128) paired over m; vbf[((bh*14 + dh*7+s)*64 + g*16+dd)*4 + ip]
    for (int idx=tid; idx<7168; idx+=256){
      int vo = idx/112, m2 = idx%112; int o = 64+vo; int m = 2*m2;
      float acc0=0.f, acc1=0.f;
      if (m<196){
        acc0=kv_b[o]; acc1=kv_b[o];
        #pragma unroll 8
        for (int c2=0;c2<64;c2++){ float w=kv_w[o*64+c2]; acc0+=s[c2*196+m]*w; acc1+=s[c2*196+m+1]*w; }
        if (m+1>=196) acc1=0.f;
      }
      int h=vo>>5, d=vo&31, dh=d>>4, dd=d&15;
      int s_=m>>5, rem=m&31, g=rem>>3, ip=(rem&7)>>1;
      vbf[(((size_t)(b*2+h)*14 + dh*7 + s_)*64 + g*16 + dd)*4 + ip] = pack_bf16(acc0, acc1);
    }
  }
}

// ---------------- K6: MFMA attention, no staging, P-only LDS ----------------
// grid: 49*128 (tile-major), block 256 (4 waves). qa/kb/v fragments loaded directly
// from pre-packed global buffers; only P (per-wave) + aliased output tile in LDS.
__global__ __launch_bounds__(256,4) void k_attn(const unsigned* __restrict__ qbf,
                       const unsigned* __restrict__ kbf, const unsigned* __restrict__ vbf,
                       const float* __restrict__ rpe, float* __restrict__ y){
  __shared__ unsigned SMEM[4*16*116];   // per-wave P bf16 [16][232]; Os (64*33 f32) aliased
  int bh = blockIdx.x & 127, tile = blockIdx.x >> 7;
  int b=bh>>1, h=bh&1, n0=tile*64, tid=threadIdx.x;
  int wv = tid>>6, l = tid&63, g = l>>4, c = l&15, qr = wv*16;

  // Q fragment: lane holds Q[row=n0+qr+c][d=8g..8g+7] (bf16 pairs, 16B)
  bf16x8 qa = *(const bf16x8*)(qbf + ((size_t)bh*NPIX + n0+qr+c)*16 + 4*g);

  const float inv_sc = 5.656854249492381f;  // sqrt(32)
  const float sc     = 0.17677669529663687f;
  const float* rp = rpe + ((size_t)(h*NPIX + n0 + qr))*196;
  f32x4 acc[13];
  #pragma unroll
  for (int mt=0; mt<12; mt++){
    #pragma unroll
    for (int r=0;r<4;r++) acc[mt][r] = rp[(size_t)(4*g+r)*196 + mt*16 + c] * inv_sc;
  }
  {
    bool v = (c<4);
    #pragma unroll
    for (int r=0;r<4;r++) acc[12][r] = v ? rp[(size_t)(4*g+r)*196 + 192 + c]*inv_sc : 0.f;
  }
  const unsigned* kB = kbf + (size_t)bh*208*16;
  #pragma unroll
  for (int mt=0; mt<13; mt++){
    bf16x8 kb = *(const bf16x8*)(kB + ((size_t)(mt*16 + c))*16 + 4*g);
    acc[mt] = __builtin_amdgcn_mfma_f32_16x16x32_bf16(qa, kb, acc[mt], 0,0,0);
  }
  #pragma unroll
  for (int mt=0;mt<13;mt++){
    #pragma unroll
    for (int r=0;r<4;r++) acc[mt][r] *= sc;
  }
  if (c>=4){
    #pragma unroll
    for (int r=0;r<4;r++) acc[12][r] = -1e30f;
  }
  // softmax per q-row (row = qr+4g+r; key index col = c across 13 tiles)
  #pragma unroll
  for (int r=0;r<4;r++){
    float mx = acc[0][r];
    #pragma unroll
    for (int mt=1;mt<13;mt++) mx = fmaxf(mx, acc[mt][r]);
    #pragma unroll
    for (int o=1;o<16;o<<=1) mx = fmaxf(mx, __shfl_xor(mx,o));
    float sm = 0.f;
    #pragma unroll
    for (int mt=0;mt<13;mt++){ float e = __expf(acc[mt][r]-mx); acc[mt][r]=e; sm += e; }
    #pragma unroll
    for (int o=1;o<16;o<<=1) sm += __shfl_xor(sm,o);
    float inv = 1.f/sm;
    #pragma unroll
    for (int mt=0;mt<13;mt++) acc[mt][r] *= inv;
  }
  // write P bf16 into own wave region (no barrier needed)
  unsigned* Pw = SMEM + wv*1856;
  #pragma unroll
  for (int mt=0;mt<13;mt++){
    #pragma unroll
    for (int r=0;r<4;r++){
      float other = __shfl_xor(acc[mt][r], 1);
      if ((l&1)==0) Pw[(4*g+r)*116 + mt*8 + (c>>1)] = pack_bf16(acc[mt][r], other);
    }
  }
  // zero pad dwords 104..111 of each row (own wave region)
  #pragma unroll
  for (int i=0;i<2;i++){ int row=(l>>3)+8*i, cc=l&7; Pw[row*116 + 104 + cc] = 0; }
  // PV: A = P (own-wave LDS), B = V fragments from global
  const short* PsS = (const short*)Pw;
  const unsigned* vB = vbf + (size_t)bh*3584;
  f32x4 o0 = {0.f,0.f,0.f,0.f}, o1 = {0.f,0.f,0.f,0.f};
  #pragma unroll
  for (int s=0;s<7;s++){
    bf16x8 pa = *(const bf16x8*)(PsS + c*232 + s*32 + 8*g);
    bf16x8 v0 = *(const bf16x8*)(vB + ((size_t)(s*64 + l))*4);
    bf16x8 v1 = *(const bf16x8*)(vB + ((size_t)((7+s)*64 + l))*4);
    o0 = __builtin_amdgcn_mfma_f32_16x16x32_bf16(pa, v0, o0, 0,0,0);
    o1 = __builtin_amdgcn_mfma_f32_16x16x32_bf16(pa, v1, o1, 0,0,0);
  }
  __syncthreads();             // all PV reads of SMEM done before Os overwrite
  float* Os = (float*)SMEM;    // [64][33]
  #pragma unroll
  for (int r=0;r<4;r++){
    Os[(qr + 4*g + r)*33 + c]      = o0[r];
    Os[(qr + 4*g + r)*33 + 16 + c] = o1[r];
  }
  __syncthreads();
  size_t base = ((size_t)(b*128 + 64 + h*32))*NPIX;
  for (int i=tid;i<2048;i+=256){ int d=i>>6, rr=i&63;
    y[base + (size_t)d*NPIX + n0 + rr] = Os[rr*33 + d]; }
}

// ---------------- K7: 3x3 depthwise p1 + bias + gelu + bn -> z1 ----------------
__global__ void k_p1(const float* __restrict__ y, const float* __restrict__ p1_w,
                     const float* __restrict__ p1_b, const float* __restrict__ p1_g,
                     const float* __restrict__ p1_bb, float* __restrict__ z1){
  int c = blockIdx.x & 127;
  __shared__ float pl[NPIX];
  const float* yp = y + (size_t)blockIdx.x*NPIX;
  for (int p=threadIdx.x;p<NPIX;p+=256) pl[p]=yp[p];
  float w9[9];
  #pragma unroll
  for (int k=0;k<9;k++) w9[k]=p1_w[c*9+k];
  float bias=p1_b[c], g=p1_g[c], bb=p1_bb[c];
  __syncthreads();
  float* zp = z1 + (size_t)blockIdx.x*NPIX;
  for (int p=threadIdx.x;p<NPIX;p+=256){
    int h=p/56, w=p%56; float acc=bias;
    #pragma unroll
    for (int i=0;i<3;i++){ int hh=h+i-1; if((unsigned)hh<56u){
      #pragma unroll
      for(int j=0;j<3;j++){ int ww=w+j-1; if((unsigned)ww<56u) acc += pl[hh*56+ww]*w9[i*3+j]; } } }
    zp[p]=gelu_f(acc)*g+bb;
  }
}

// ---------------- K8: fused pointwise 128->16->128 + residual ----------------
__global__ void k_p23(const float* __restrict__ z1, const float* __restrict__ y,
                      const float* __restrict__ p2_w, const float* __restrict__ p2_b,
                      const float* __restrict__ p2_g, const float* __restrict__ p2_bb,
                      const float* __restrict__ p3_w, const float* __restrict__ p3_b,
                      const float* __restrict__ p3_g, const float* __restrict__ p3_bb,
                      float* __restrict__ out){
  int b=blockIdx.x/13, t=blockIdx.x%13; int n=t*256+threadIdx.x;
  if (n>=NPIX) return;
  const float* zp = z1 + (size_t)b*128*NPIX + n;
  float acc[16];
  #pragma unroll
  for (int i=0;i<16;i++) acc[i]=p2_b[i];
  #pragma unroll 4
  for (int c2=0;c2<128;c2++){
    float v = zp[(size_t)c2*NPIX];
    #pragma unroll
    for(int i=0;i<16;i++) acc[i]+=v*p2_w[i*128+c2];
  }
  float t16[16];
  #pragma unroll
  for(int i=0;i<16;i++) t16[i] = gelu_f(acc[i])*p2_g[i]+p2_bb[i];
  const float* yp = y + (size_t)b*128*NPIX + n;
  float* op = out + (size_t)b*128*NPIX + n;
  for (int o=0;o<128;o++){
    float a=p3_b[o];
    #pragma unroll
    for(int i=0;i<16;i++) a+=t16[i]*p3_w[o*16+i];
    op[(size_t)o*NPIX] = a*p3_g[o]+p3_bb[o] + yp[(size_t)o*NPIX];
  }
}

// ---------------- launch ----------------
extern "C" void kernel_launch(void* const* d_in, const int* in_sizes, int n_in,
                              void* d_out, int out_size, void* d_ws, size_t ws_size,
                              hipStream_t stream) {
  (void)in_sizes; (void)n_in; (void)out_size; (void)ws_size;
  const float* x       = (const float*)d_in[0];
  const float* rpe     = (const float*)d_in[1];
  const float* dc_w    = (const float*)d_in[2];
  const float* dc_b    = (const float*)d_in[3];
  const float* dcp1_w  = (const float*)d_in[4];
  const float* dcp1_g  = (const float*)d_in[5];
  const float* dcp1_b  = (const float*)d_in[6];
  const float* dcp2_w  = (const float*)d_in[7];
  const float* dcp2_b  = (const float*)d_in[8];
  const float* q_w     = (const float*)d_in[9];
  const float* q_b     = (const float*)d_in[10];
  const float* kv_w    = (const float*)d_in[11];
  const float* kv_b    = (const float*)d_in[12];
  const float* sr1_w   = (const float*)d_in[13];
  const float* sr1_g   = (const float*)d_in[14];
  const float* sr1_b   = (const float*)d_in[15];
  const float* sr2_w   = (const float*)d_in[16];
  const float* sr2_g   = (const float*)d_in[17];
  const float* sr2_b   = (const float*)d_in[18];
  const float* lc_w    = (const float*)d_in[19];
  const float* lc_b    = (const float*)d_in[20];
  const float* p1_w    = (const float*)d_in[21];
  const float* p1_b    = (const float*)d_in[22];
  const float* p1_g    = (const float*)d_in[23];
  const float* p1_bb   = (const float*)d_in[24];
  const float* p2_w    = (const float*)d_in[25];
  const float* p2_b    = (const float*)d_in[26];
  const float* p2_g    = (const float*)d_in[27];
  const float* p2_bb   = (const float*)d_in[28];
  const float* p3_w    = (const float*)d_in[29];
  const float* p3_b    = (const float*)d_in[30];
  const float* p3_g    = (const float*)d_in[31];
  const float* p3_bb   = (const float*)d_in[32];
  float* out = (float*)d_out;
  float* ws  = (float*)d_ws;

  const size_t OFF_Y     = 0;           // y (25.69M floats)
  const size_t OFF_A     = 25690112;    // qbf (6.42M dwords) then z1 (25.69M f32)
  const size_t OFF_POOL  = 54591488;
  const size_t OFF_XMEAN = 54628352;
  const size_t OFF_W     = 54632448;
  const size_t OFF_DB    = 54669312;
  const size_t OFF_KV2   = 54673408;
  const size_t OFF_KV3   = 55476224;
  const size_t OFF_K     = 56279040;    // kbf: 425,984 dwords
  const size_t OFF_V     = 57081856;    // vbf: 458,752 dwords

  float*    yb    = ws + OFF_Y;
  unsigned* qbf   = (unsigned*)(ws + OFF_A);
  float*    z1    = ws + OFF_A;
  float*    pool  = ws + OFF_POOL;
  float*    xmean = ws + OFF_XMEAN;
  float*    wgt   = ws + OFF_W;
  float*    dbias = ws + OFF_DB;
  float*    kv2   = ws + OFF_KV2;
  float*    kv3   = ws + OFF_KV3;
  unsigned* kbf   = (unsigned*)(ws + OFF_K);
  unsigned* vbf   = (unsigned*)(ws + OFF_V);

  k_pool  <<<4096, 64, 0, stream>>>(x, pool, xmean);
  k_dcproj<<<64, 256, 0, stream>>>(pool, xmean, dcp1_w, dcp1_g, dcp1_b, dcp2_w, dcp2_b, dc_w, dc_b, wgt, dbias);
  k_y1    <<<4096, 256, 0, stream>>>(x, wgt, dbias, yb);
  k_qproj <<<3136, 256, 0, stream>>>(x, q_w, q_b, qbf);
  k_sr    <<<4096, 256, 0, stream>>>(x, sr1_w, sr1_g, sr1_b, sr2_w, sr2_g, sr2_b, kv2);
  k_lc    <<<4096, 256, 0, stream>>>(kv2, lc_w, lc_b, kv3);
  k_kv    <<<128, 256, 0, stream>>>(kv3, kv_w, kv_b, kbf, vbf);
  k_attn  <<<6272, 256, 0, stream>>>(qbf, kbf, vbf, rpe, yb);
  k_p1    <<<8192, 256, 0, stream>>>(yb, p1_w, p1_b, p1_g, p1_bb, z1);
  k_p23   <<<832, 256, 0, stream>>>(z1, yb, p2_w, p2_b, p2_g, p2_bb, p3_w, p3_b, p3_g, p3_bb, out);
}